// Round 3
// baseline (281.691 us; speedup 1.0000x reference)
//
#include <hip/hip_runtime.h>

// MultiCamNoiseCropV3Prompter: out = x + prompt broadcast over T frames.
// R5 == R4 resubmit (previous round died on container acquire, not kernel).
// Single fused kernel, TGRP=8 frames per thread.
// Evidence so far: top-5 dispatches are all harness poison-fills (~93 us,
// 6.5 TB/s); our kernel is <=92 us of the 263 us window. Floor for the
// kernel = 308 MB / 6.3 TB/s ~= 49 us. Probes three deltas vs the
// known-good m13 streaming shape:
//   1) plain (cached) loads -- NT hint kept ONLY on stores (out never re-read)
//   2) readfirstlane(b) -> scalar s_load for cam/offsets (b is block-uniform:
//      12544 items per (b,c,tg) = exactly 49 blocks, no straddling)
//   3) 1176 blocks (single resident cohort, no 2048-capacity quantization),
//      8 explicit in-flight float4 loads per thread (xv[8] array, issued
//      before the prompt VALU/gather section so latency hides under it)

#define PP 30
#define SS 224
#define CROPC 164
#define BB 16
#define TT 16
#define TGRP 8

typedef float f4 __attribute__((ext_vector_type(4)));

__device__ __forceinline__ void interp1d(float pos, float in_size, int in_size_i,
                                         int out_size, int& i0, int& i1, float& w) {
    float scale = in_size / (float)out_size;
    float f = fmaxf((pos + 0.5f) * scale - 0.5f, 0.0f);
    i0 = (int)floorf(f);
    w = f - (float)i0;
    i1 = min(i0 + 1, in_size_i - 1);
}

__global__ void __launch_bounds__(256)
fused8_kernel(const float* __restrict__ x,
              const float* __restrict__ pu,   // [3,3,2P,S]
              const float* __restrict__ pd,   // [3,3,P,S]
              const float* __restrict__ pl,   // [3,3,CROP,2P]
              const float* __restrict__ pr,   // [3,3,CROP,P]
              const int* __restrict__ cam_views,
              const int* __restrict__ offs_r,
              const int* __restrict__ offs_d,
              float* __restrict__ out) {
    const int J4 = SS / 4;     // 56
    const int NG = TT / TGRP;  // 2 frame-groups
    int idx = blockIdx.x * blockDim.x + threadIdx.x;
    const int total = BB * 3 * NG * SS * J4;  // 301,056 = 1176 * 256 exactly
    if (idx >= total) return;

    // idx = (((b*3 + c)*NG + tg)*SS + i)*J4 + j4  -- j4 fastest => coalesced
    int j4 = idx % J4;
    int tmp = idx / J4;
    int i = tmp % SS;
    tmp /= SS;
    int tg = tmp % NG;
    tmp /= NG;
    int c = tmp % 3;
    int b = tmp / 3;

    const int j0 = j4 * 4;

    // ---- issue the 8 streaming x loads FIRST; prompt work hides under them.
    size_t base = (((size_t)(b * 3 + c) * TT + (size_t)tg * TGRP) * (SS * SS))
                  + (size_t)i * SS + j0;
    f4 xv[TGRP];
    #pragma unroll
    for (int k = 0; k < TGRP; k++)
        xv[k] = *reinterpret_cast<const f4*>(x + base + (size_t)k * (SS * SS));

    // ---- per-sample params: b is block-uniform -> force scalar loads.
    const int bu = __builtin_amdgcn_readfirstlane(b);
    const int cam = cam_views[bu];
    const int off_r = offs_r[bu];
    const int off_d = offs_d[bu];
    const int off_l = 2 * PP - off_r;
    const int off_u = 2 * PP - off_d;

    const float* puc = pu + (size_t)(cam * 3 + c) * (2 * PP) * SS;
    const float* pdc = pd + (size_t)(cam * 3 + c) * PP * SS;
    const float* plc = pl + (size_t)(cam * 3 + c) * CROPC * (2 * PP);
    const float* prc = pr + (size_t)(cam * 3 + c) * CROPC * PP;

    // ---- prompt value for (b, c, i, j0..j0+3), computed in registers.
    float pv[4];
    if (i < off_u) {
        int r0, r1; float w;
        interp1d((float)i, (float)(2 * PP), 2 * PP, off_u, r0, r1, w);
        const float* a  = puc + (size_t)r0 * SS + j0;
        const float* bp = puc + (size_t)r1 * SS + j0;
        #pragma unroll
        for (int k = 0; k < 4; k++)
            pv[k] = a[k] * (1.0f - w) + bp[k] * w;
    } else if (i >= SS - off_d) {
        int r0, r1; float w;
        interp1d((float)(i - (SS - off_d)), (float)PP, PP, off_d, r0, r1, w);
        const float* a  = pdc + (size_t)r0 * SS + j0;
        const float* bp = pdc + (size_t)r1 * SS + j0;
        #pragma unroll
        for (int k = 0; k < 4; k++)
            pv[k] = a[k] * (1.0f - w) + bp[k] * w;
    } else {
        const int r = i - off_u;
        const float* plr = plc + (size_t)r * (2 * PP);
        const float* prr = prc + (size_t)r * PP;
        #pragma unroll
        for (int k = 0; k < 4; k++) {
            int j = j0 + k;
            float v = 0.0f;
            if (j < off_l) {
                int c0, c1; float w;
                interp1d((float)j, (float)(2 * PP), 2 * PP, off_l, c0, c1, w);
                v = plr[c0] * (1.0f - w) + plr[c1] * w;
            } else if (j >= SS - off_r) {
                int c0, c1; float w;
                interp1d((float)(j - (SS - off_r)), (float)PP, PP, off_r, c0, c1, w);
                v = prr[c0] * (1.0f - w) + prr[c1] * w;
            }
            pv[k] = v;
        }
    }

    // ---- add + streaming (non-temporal) stores.
    #pragma unroll
    for (int k = 0; k < TGRP; k++) {
        f4 ov = xv[k];
        ov[0] += pv[0];
        ov[1] += pv[1];
        ov[2] += pv[2];
        ov[3] += pv[3];
        __builtin_nontemporal_store(
            ov, reinterpret_cast<f4*>(out + base + (size_t)k * (SS * SS)));
    }
}

extern "C" void kernel_launch(void* const* d_in, const int* in_sizes, int n_in,
                              void* d_out, int out_size, void* d_ws, size_t ws_size,
                              hipStream_t stream) {
    const float* x  = (const float*)d_in[0];
    const float* pu = (const float*)d_in[1];
    const float* pd = (const float*)d_in[2];
    const float* pl = (const float*)d_in[3];
    const float* pr = (const float*)d_in[4];
    const int* cam  = (const int*)d_in[5];
    const int* orr  = (const int*)d_in[6];
    const int* od   = (const int*)d_in[7];
    float* out = (float*)d_out;

    const int total = BB * 3 * (TT / TGRP) * SS * (SS / 4);  // 301,056
    fused8_kernel<<<(total + 255) / 256, 256, 0, stream>>>(
        x, pu, pd, pl, pr, cam, orr, od, out);
}

// Round 4
// 278.287 us; speedup vs baseline: 1.0122x; 1.0122x over previous
//
#include <hip/hip_runtime.h>

// MultiCamNoiseCropV3Prompter: out = x + prompt broadcast over T frames.
// R6: TGRP=4 (restore full occupancy) + plain cached loads + NT stores.
// Counter evidence (R5, TGRP=8): 97 us, 2.4 TB/s, Occupancy 65%, VALU 6.3%
//   -> latency/occupancy-bound, not BW/VALU-bound. 1176 blocks = 4.6/CU.
// TGRP=4 -> 2352 blocks = 9.2/CU -> 8 resident (32 waves/CU, full).
// R5 also proved FETCH=82 MB with plain loads: L3 (256 MB) serves ~half of x
// in steady state (NT stores keep `out` from evicting it). True traffic
// ~236 MB -> ~37 us floor. R3 (TGRP=4, NT loads) ~= 79 us back-solved.

#define PP 30
#define SS 224
#define CROPC 164
#define BB 16
#define TT 16
#define TGRP 4

typedef float f4 __attribute__((ext_vector_type(4)));

__device__ __forceinline__ void interp1d(float pos, float in_size, int in_size_i,
                                         int out_size, int& i0, int& i1, float& w) {
    float scale = in_size / (float)out_size;
    float f = fmaxf((pos + 0.5f) * scale - 0.5f, 0.0f);
    i0 = (int)floorf(f);
    w = f - (float)i0;
    i1 = min(i0 + 1, in_size_i - 1);
}

__global__ void __launch_bounds__(256)
fused4_kernel(const float* __restrict__ x,
              const float* __restrict__ pu,   // [3,3,2P,S]
              const float* __restrict__ pd,   // [3,3,P,S]
              const float* __restrict__ pl,   // [3,3,CROP,2P]
              const float* __restrict__ pr,   // [3,3,CROP,P]
              const int* __restrict__ cam_views,
              const int* __restrict__ offs_r,
              const int* __restrict__ offs_d,
              float* __restrict__ out) {
    const int J4 = SS / 4;     // 56
    const int NG = TT / TGRP;  // 4 frame-groups
    int idx = blockIdx.x * blockDim.x + threadIdx.x;
    // total = 16*3*4*224*56 = 602,112 = 2352 blocks * 256, exact grid.

    // idx = (((b*3 + c)*NG + tg)*SS + i)*J4 + j4  -- j4 fastest => coalesced
    int j4 = idx % J4;
    int tmp = idx / J4;
    int i = tmp % SS;
    tmp /= SS;
    int tg = tmp % NG;
    tmp /= NG;
    int c = tmp % 3;
    int b = tmp / 3;

    const int j0 = j4 * 4;

    // ---- issue the 4 x loads FIRST (plain/cached: L3 serves ~half of x);
    // prompt work hides under them.
    size_t base = (((size_t)(b * 3 + c) * TT + (size_t)tg * TGRP) * (SS * SS))
                  + (size_t)i * SS + j0;
    f4 xv[TGRP];
    #pragma unroll
    for (int k = 0; k < TGRP; k++)
        xv[k] = *reinterpret_cast<const f4*>(x + base + (size_t)k * (SS * SS));

    // ---- per-sample params: b is block-uniform (b spans 588 whole blocks)
    // -> force scalar loads.
    const int bu = __builtin_amdgcn_readfirstlane(b);
    const int cam = cam_views[bu];
    const int off_r = offs_r[bu];
    const int off_d = offs_d[bu];
    const int off_l = 2 * PP - off_r;
    const int off_u = 2 * PP - off_d;

    const float* puc = pu + (size_t)(cam * 3 + c) * (2 * PP) * SS;
    const float* pdc = pd + (size_t)(cam * 3 + c) * PP * SS;
    const float* plc = pl + (size_t)(cam * 3 + c) * CROPC * (2 * PP);
    const float* prc = pr + (size_t)(cam * 3 + c) * CROPC * PP;

    // ---- prompt value for (b, c, i, j0..j0+3), computed in registers.
    float pv[4];
    if (i < off_u) {
        int r0, r1; float w;
        interp1d((float)i, (float)(2 * PP), 2 * PP, off_u, r0, r1, w);
        const float* a  = puc + (size_t)r0 * SS + j0;
        const float* bp = puc + (size_t)r1 * SS + j0;
        #pragma unroll
        for (int k = 0; k < 4; k++)
            pv[k] = a[k] * (1.0f - w) + bp[k] * w;
    } else if (i >= SS - off_d) {
        int r0, r1; float w;
        interp1d((float)(i - (SS - off_d)), (float)PP, PP, off_d, r0, r1, w);
        const float* a  = pdc + (size_t)r0 * SS + j0;
        const float* bp = pdc + (size_t)r1 * SS + j0;
        #pragma unroll
        for (int k = 0; k < 4; k++)
            pv[k] = a[k] * (1.0f - w) + bp[k] * w;
    } else {
        const int r = i - off_u;
        const float* plr = plc + (size_t)r * (2 * PP);
        const float* prr = prc + (size_t)r * PP;
        #pragma unroll
        for (int k = 0; k < 4; k++) {
            int j = j0 + k;
            float v = 0.0f;
            if (j < off_l) {
                int c0, c1; float w;
                interp1d((float)j, (float)(2 * PP), 2 * PP, off_l, c0, c1, w);
                v = plr[c0] * (1.0f - w) + plr[c1] * w;
            } else if (j >= SS - off_r) {
                int c0, c1; float w;
                interp1d((float)(j - (SS - off_r)), (float)PP, PP, off_r, c0, c1, w);
                v = prr[c0] * (1.0f - w) + prr[c1] * w;
            }
            pv[k] = v;
        }
    }

    // ---- add + streaming (non-temporal) stores: out is never re-read, and
    // NT keeps `out` from evicting x's L3 residency (FETCH=82MB measured).
    #pragma unroll
    for (int k = 0; k < TGRP; k++) {
        f4 ov = xv[k];
        ov[0] += pv[0];
        ov[1] += pv[1];
        ov[2] += pv[2];
        ov[3] += pv[3];
        __builtin_nontemporal_store(
            ov, reinterpret_cast<f4*>(out + base + (size_t)k * (SS * SS)));
    }
}

extern "C" void kernel_launch(void* const* d_in, const int* in_sizes, int n_in,
                              void* d_out, int out_size, void* d_ws, size_t ws_size,
                              hipStream_t stream) {
    const float* x  = (const float*)d_in[0];
    const float* pu = (const float*)d_in[1];
    const float* pd = (const float*)d_in[2];
    const float* pl = (const float*)d_in[3];
    const float* pr = (const float*)d_in[4];
    const int* cam  = (const int*)d_in[5];
    const int* orr  = (const int*)d_in[6];
    const int* od   = (const int*)d_in[7];
    float* out = (float*)d_out;

    const int total = BB * 3 * (TT / TGRP) * SS * (SS / 4);  // 602,112
    fused4_kernel<<<total / 256, 256, 0, stream>>>(
        x, pu, pd, pl, pr, cam, orr, od, out);
}

// Round 5
// 277.265 us; speedup vs baseline: 1.0160x; 1.0037x over previous
//
#include <hip/hip_runtime.h>

// MultiCamNoiseCropV3Prompter: out = x + prompt broadcast over T frames.
// R7: R6 with NT stores REMOVED (plain stores). Single-variable experiment.
// Evidence: R5 (TGRP=8) and R6 (TGRP=4) both stuck at 2.4-2.5 TB/s, 95-97us,
// VALU 12%, Occ 66% -- no pipe saturated; occupancy exonerated (fills hit
// 6.5 TB/s at 9.7% occ). NT store is the one delta vs every known-good
// 6+ TB/s streaming writer (m13 copy, rocclr fills). Theory: nt bit defeats
// L2 write-combining on streaming lines; stores backpressure the wave.
// Predict: 95 -> 55-65 us, 3.8-4.5 TB/s. If unchanged, NT exonerated ->
// next probe is control pure-add + frame-linear store pattern.

#define PP 30
#define SS 224
#define CROPC 164
#define BB 16
#define TT 16
#define TGRP 4

typedef float f4 __attribute__((ext_vector_type(4)));

__device__ __forceinline__ void interp1d(float pos, float in_size, int in_size_i,
                                         int out_size, int& i0, int& i1, float& w) {
    float scale = in_size / (float)out_size;
    float f = fmaxf((pos + 0.5f) * scale - 0.5f, 0.0f);
    i0 = (int)floorf(f);
    w = f - (float)i0;
    i1 = min(i0 + 1, in_size_i - 1);
}

__global__ void __launch_bounds__(256)
fused4_kernel(const float* __restrict__ x,
              const float* __restrict__ pu,   // [3,3,2P,S]
              const float* __restrict__ pd,   // [3,3,P,S]
              const float* __restrict__ pl,   // [3,3,CROP,2P]
              const float* __restrict__ pr,   // [3,3,CROP,P]
              const int* __restrict__ cam_views,
              const int* __restrict__ offs_r,
              const int* __restrict__ offs_d,
              float* __restrict__ out) {
    const int J4 = SS / 4;     // 56
    const int NG = TT / TGRP;  // 4 frame-groups
    int idx = blockIdx.x * blockDim.x + threadIdx.x;
    // total = 16*3*4*224*56 = 602,112 = 2352 blocks * 256, exact grid.

    // idx = (((b*3 + c)*NG + tg)*SS + i)*J4 + j4  -- j4 fastest => coalesced
    int j4 = idx % J4;
    int tmp = idx / J4;
    int i = tmp % SS;
    tmp /= SS;
    int tg = tmp % NG;
    tmp /= NG;
    int c = tmp % 3;
    int b = tmp / 3;

    const int j0 = j4 * 4;

    // ---- issue the 4 x loads FIRST; prompt work hides under them.
    size_t base = (((size_t)(b * 3 + c) * TT + (size_t)tg * TGRP) * (SS * SS))
                  + (size_t)i * SS + j0;
    f4 xv[TGRP];
    #pragma unroll
    for (int k = 0; k < TGRP; k++)
        xv[k] = *reinterpret_cast<const f4*>(x + base + (size_t)k * (SS * SS));

    // ---- per-sample params: b is block-uniform (b spans 588 whole blocks)
    // -> force scalar loads.
    const int bu = __builtin_amdgcn_readfirstlane(b);
    const int cam = cam_views[bu];
    const int off_r = offs_r[bu];
    const int off_d = offs_d[bu];
    const int off_l = 2 * PP - off_r;
    const int off_u = 2 * PP - off_d;

    const float* puc = pu + (size_t)(cam * 3 + c) * (2 * PP) * SS;
    const float* pdc = pd + (size_t)(cam * 3 + c) * PP * SS;
    const float* plc = pl + (size_t)(cam * 3 + c) * CROPC * (2 * PP);
    const float* prc = pr + (size_t)(cam * 3 + c) * CROPC * PP;

    // ---- prompt value for (b, c, i, j0..j0+3), computed in registers.
    float pv[4];
    if (i < off_u) {
        int r0, r1; float w;
        interp1d((float)i, (float)(2 * PP), 2 * PP, off_u, r0, r1, w);
        const float* a  = puc + (size_t)r0 * SS + j0;
        const float* bp = puc + (size_t)r1 * SS + j0;
        #pragma unroll
        for (int k = 0; k < 4; k++)
            pv[k] = a[k] * (1.0f - w) + bp[k] * w;
    } else if (i >= SS - off_d) {
        int r0, r1; float w;
        interp1d((float)(i - (SS - off_d)), (float)PP, PP, off_d, r0, r1, w);
        const float* a  = pdc + (size_t)r0 * SS + j0;
        const float* bp = pdc + (size_t)r1 * SS + j0;
        #pragma unroll
        for (int k = 0; k < 4; k++)
            pv[k] = a[k] * (1.0f - w) + bp[k] * w;
    } else {
        const int r = i - off_u;
        const float* plr = plc + (size_t)r * (2 * PP);
        const float* prr = prc + (size_t)r * PP;
        #pragma unroll
        for (int k = 0; k < 4; k++) {
            int j = j0 + k;
            float v = 0.0f;
            if (j < off_l) {
                int c0, c1; float w;
                interp1d((float)j, (float)(2 * PP), 2 * PP, off_l, c0, c1, w);
                v = plr[c0] * (1.0f - w) + plr[c1] * w;
            } else if (j >= SS - off_r) {
                int c0, c1; float w;
                interp1d((float)(j - (SS - off_r)), (float)PP, PP, off_r, c0, c1, w);
                v = prr[c0] * (1.0f - w) + prr[c1] * w;
            }
            pv[k] = v;
        }
    }

    // ---- add + PLAIN stores (the experiment: no non-temporal hint).
    #pragma unroll
    for (int k = 0; k < TGRP; k++) {
        f4 ov = xv[k];
        ov[0] += pv[0];
        ov[1] += pv[1];
        ov[2] += pv[2];
        ov[3] += pv[3];
        *reinterpret_cast<f4*>(out + base + (size_t)k * (SS * SS)) = ov;
    }
}

extern "C" void kernel_launch(void* const* d_in, const int* in_sizes, int n_in,
                              void* d_out, int out_size, void* d_ws, size_t ws_size,
                              hipStream_t stream) {
    const float* x  = (const float*)d_in[0];
    const float* pu = (const float*)d_in[1];
    const float* pd = (const float*)d_in[2];
    const float* pl = (const float*)d_in[3];
    const float* pr = (const float*)d_in[4];
    const int* cam  = (const int*)d_in[5];
    const int* orr  = (const int*)d_in[6];
    const int* od   = (const int*)d_in[7];
    float* out = (float*)d_out;

    const int total = BB * 3 * (TT / TGRP) * SS * (SS / 4);  // 602,112
    fused4_kernel<<<total / 256, 256, 0, stream>>>(
        x, pu, pd, pl, pr, cam, orr, od, out);
}

// Round 6
// 269.223 us; speedup vs baseline: 1.0463x; 1.0299x over previous
//
#include <hip/hip_runtime.h>

// MultiCamNoiseCropV3Prompter: out = x + prompt broadcast over T frames.
// R8: fused, ONE float4/thread, FULLY LINEAR sweep in out/x memory order.
// Evidence: TGRP=8/4 x NT/plain all stuck at 2.4-2.6 TB/s (93-97us) with no
// pipe saturated (VALU 12%, Occ 66%). The only remaining delta vs the
// 6.5 TB/s writers (rocclr fill, m13 copy, R2 stream_add) is access shape:
// fused-TGRP kernels stream ~768 concurrent 200KB frame-slices (4 loads per
// thread at 200KB stride); the fast kernels are a single dense linear front.
// R8 mirrors the fill's shape exactly: wave = 1KB contiguous load+store,
// consecutive blocks = consecutive addresses. Prompt recomputed per frame
// (x16 redundant VALU, est. 25-45% VALUBusy -- under the BW ceiling).

#define PP 30
#define SS 224
#define CROPC 164
#define BB 16
#define TT 16

typedef float f4 __attribute__((ext_vector_type(4)));

__device__ __forceinline__ void interp1d(float pos, float in_size, int in_size_i,
                                         int out_size, int& i0, int& i1, float& w) {
    float scale = in_size / (float)out_size;
    float f = fmaxf((pos + 0.5f) * scale - 0.5f, 0.0f);
    i0 = (int)floorf(f);
    w = f - (float)i0;
    i1 = min(i0 + 1, in_size_i - 1);
}

__global__ void __launch_bounds__(256)
fused_linear_kernel(const float* __restrict__ x,
                    const float* __restrict__ pu,   // [3,3,2P,S]
                    const float* __restrict__ pd,   // [3,3,P,S]
                    const float* __restrict__ pl,   // [3,3,CROP,2P]
                    const float* __restrict__ pr,   // [3,3,CROP,P]
                    const int* __restrict__ cam_views,
                    const int* __restrict__ offs_r,
                    const int* __restrict__ offs_d,
                    float* __restrict__ out) {
    const int J4 = SS / 4;  // 56
    int idx = blockIdx.x * blockDim.x + threadIdx.x;
    // total = 16*3*16*224*56 = 2,408,448 = 9408 blocks * 256, exact grid.
    // Linear layout: idx = ((((b*3+c)*TT + t)*SS) + i)*J4 + j4

    // ---- issue the x load FIRST; everything else hides under it.
    const f4 xv = *reinterpret_cast<const f4*>(x + (size_t)idx * 4);

    int j4 = idx % J4;
    int tmp = idx / J4;
    int i = tmp % SS;
    tmp /= SS;           // tmp = (b*3+c)*TT + t
    int bc = tmp / TT;   // b*3 + c
    int c = bc % 3;
    int b = bc / 3;

    const int j0 = j4 * 4;

    // ---- per-sample params: b is block-uniform (588 whole blocks per b)
    // -> force scalar loads.
    const int bu = __builtin_amdgcn_readfirstlane(b);
    const int cam = cam_views[bu];
    const int off_r = offs_r[bu];
    const int off_d = offs_d[bu];
    const int off_l = 2 * PP - off_r;
    const int off_u = 2 * PP - off_d;

    const float* puc = pu + (size_t)(cam * 3 + c) * (2 * PP) * SS;
    const float* pdc = pd + (size_t)(cam * 3 + c) * PP * SS;
    const float* plc = pl + (size_t)(cam * 3 + c) * CROPC * (2 * PP);
    const float* prc = pr + (size_t)(cam * 3 + c) * CROPC * PP;

    // ---- prompt value for (b, c, i, j0..j0+3), computed in registers.
    float pv[4];
    if (i < off_u) {
        int r0, r1; float w;
        interp1d((float)i, (float)(2 * PP), 2 * PP, off_u, r0, r1, w);
        const float* a  = puc + (size_t)r0 * SS + j0;
        const float* bp = puc + (size_t)r1 * SS + j0;
        #pragma unroll
        for (int k = 0; k < 4; k++)
            pv[k] = a[k] * (1.0f - w) + bp[k] * w;
    } else if (i >= SS - off_d) {
        int r0, r1; float w;
        interp1d((float)(i - (SS - off_d)), (float)PP, PP, off_d, r0, r1, w);
        const float* a  = pdc + (size_t)r0 * SS + j0;
        const float* bp = pdc + (size_t)r1 * SS + j0;
        #pragma unroll
        for (int k = 0; k < 4; k++)
            pv[k] = a[k] * (1.0f - w) + bp[k] * w;
    } else {
        const int r = i - off_u;
        const float* plr = plc + (size_t)r * (2 * PP);
        const float* prr = prc + (size_t)r * PP;
        #pragma unroll
        for (int k = 0; k < 4; k++) {
            int j = j0 + k;
            float v = 0.0f;
            if (j < off_l) {
                int c0, c1; float w;
                interp1d((float)j, (float)(2 * PP), 2 * PP, off_l, c0, c1, w);
                v = plr[c0] * (1.0f - w) + plr[c1] * w;
            } else if (j >= SS - off_r) {
                int c0, c1; float w;
                interp1d((float)(j - (SS - off_r)), (float)PP, PP, off_r, c0, c1, w);
                v = prr[c0] * (1.0f - w) + prr[c1] * w;
            }
            pv[k] = v;
        }
    }

    // ---- add + plain store, same linear address.
    f4 ov = xv;
    ov[0] += pv[0];
    ov[1] += pv[1];
    ov[2] += pv[2];
    ov[3] += pv[3];
    *reinterpret_cast<f4*>(out + (size_t)idx * 4) = ov;
}

extern "C" void kernel_launch(void* const* d_in, const int* in_sizes, int n_in,
                              void* d_out, int out_size, void* d_ws, size_t ws_size,
                              hipStream_t stream) {
    const float* x  = (const float*)d_in[0];
    const float* pu = (const float*)d_in[1];
    const float* pd = (const float*)d_in[2];
    const float* pl = (const float*)d_in[3];
    const float* pr = (const float*)d_in[4];
    const int* cam  = (const int*)d_in[5];
    const int* orr  = (const int*)d_in[6];
    const int* od   = (const int*)d_in[7];
    float* out = (float*)d_out;

    const int total = BB * 3 * TT * SS * (SS / 4);  // 2,408,448
    fused_linear_kernel<<<total / 256, 256, 0, stream>>>(
        x, pu, pd, pl, pr, cam, orr, od, out);
}